// Round 13
// baseline (339.215 us; speedup 1.0000x reference)
//
#include <hip/hip_runtime.h>
#include <cstddef>
#include <cstdint>

constexpr int cN0 = 100000, cN1 = 50000, cN2 = 25000;
constexpr int cE0 = 400000, cE1 = 200000;
constexpr float SLOPE = 0.2f;

typedef short short8  __attribute__((ext_vector_type(8)));
typedef float f32x4   __attribute__((ext_vector_type(4)));

__device__ __forceinline__ unsigned short f2bf(float x) {
    union { float f; uint32_t u; } c; c.f = x;
    uint32_t u = c.u + 0x7FFFu + ((c.u >> 16) & 1u);   // RNE
    return (unsigned short)(u >> 16);
}
__device__ __forceinline__ float bf2f(uint32_t u) {
    union { uint32_t u; float f; } c; c.u = u << 16; return c.f;
}
__device__ __forceinline__ float lrelu(float x) { return x >= 0.f ? x : SLOPE * x; }

__device__ __forceinline__ uint32_t cvtpk(float lo, float hi) {
    uint32_t r;
    asm("v_cvt_pk_bf16_f32 %0, %1, %2" : "=v"(r) : "v"(lo), "v"(hi));
    return r;
}

// async global->LDS, 16B per lane; lds dst is wave-uniform base (HW adds lane*16)
__device__ __forceinline__ void gload_lds16(const void* g, void* l) {
    __builtin_amdgcn_global_load_lds(
        (const __attribute__((address_space(1))) unsigned int*)g,
        (__attribute__((address_space(3))) unsigned int*)l, 16, 0, 0);
}

// ---------------- CSR build (merged across both layers) ----------------

__global__ void hist2_kernel(const int* __restrict__ d0, const int* __restrict__ d1,
                             int* __restrict__ cnt0, int* __restrict__ cnt1) {
    int i = blockIdx.x * blockDim.x + threadIdx.x;
    if (i < cE0) atomicAdd(&cnt0[d0[i]], 1);
    int j = i - cE0;
    if (j >= 0 && j < cE1) atomicAdd(&cnt1[d1[j]], 1);
}

__global__ __launch_bounds__(256) void chunk_sum2_kernel(const int* __restrict__ cnt0, int n0,
                                                         const int* __restrict__ cnt1, int n1,
                                                         int* __restrict__ bsum0, int* __restrict__ bsum1,
                                                         int nblk1) {
    const int* cnt = blockIdx.y ? cnt1 : cnt0;
    int n = blockIdx.y ? n1 : n0;
    int* bsum = blockIdx.y ? bsum1 : bsum0;
    if (blockIdx.y && (int)blockIdx.x >= nblk1) return;
    int i = blockIdx.x * 256 + threadIdx.x;
    int v = (i < n) ? cnt[i] : 0;
    #pragma unroll
    for (int o = 32; o; o >>= 1) v += __shfl_xor(v, o);
    __shared__ int ws[4];
    if ((threadIdx.x & 63) == 0) ws[threadIdx.x >> 6] = v;
    __syncthreads();
    if (threadIdx.x == 0) bsum[blockIdx.x] = ws[0] + ws[1] + ws[2] + ws[3];
}

__device__ __forceinline__ int block_exscan(int v, int& total) {
    int lane = threadIdx.x & 63, w = threadIdx.x >> 6;
    int x = v;
    #pragma unroll
    for (int o = 1; o < 64; o <<= 1) { int t = __shfl_up(x, o); if (lane >= o) x += t; }
    __shared__ int ws[4];
    if (lane == 63) ws[w] = x;
    __syncthreads();
    int add = 0;
    #pragma unroll
    for (int i = 0; i < 4; ++i) if (i < w) add += ws[i];
    total = ws[0] + ws[1] + ws[2] + ws[3];
    return add + x - v;
}

__global__ __launch_bounds__(256) void top_scan2_kernel(const int* __restrict__ bsum0, int nblk0,
                                                        const int* __restrict__ bsum1, int nblk1,
                                                        int* __restrict__ boff0, int* __restrict__ boff1,
                                                        int* __restrict__ tot0, int* __restrict__ tot1) {
    int i = threadIdx.x;
    int tot;
    int v = (i < nblk0) ? bsum0[i] : 0;
    int e = block_exscan(v, tot);
    if (i < nblk0) boff0[i] = e;
    if (i == 0) *tot0 = tot;
    __syncthreads();
    v = (i < nblk1) ? bsum1[i] : 0;
    e = block_exscan(v, tot);
    if (i < nblk1) boff1[i] = e;
    if (i == 0) *tot1 = tot;
}

__global__ __launch_bounds__(256) void chunk_scan2_kernel(const int* __restrict__ cnt0, int n0,
                                                          const int* __restrict__ cnt1, int n1,
                                                          const int* __restrict__ boff0, const int* __restrict__ boff1,
                                                          int* __restrict__ offs0, int* __restrict__ cursor0,
                                                          int* __restrict__ offs1, int* __restrict__ cursor1,
                                                          int nblk1) {
    const int* cnt = blockIdx.y ? cnt1 : cnt0;
    const int* boff = blockIdx.y ? boff1 : boff0;
    int* offs = blockIdx.y ? offs1 : offs0;
    int* cursor = blockIdx.y ? cursor1 : cursor0;
    int n = blockIdx.y ? n1 : n0;
    if (blockIdx.y && (int)blockIdx.x >= nblk1) return;
    int i = blockIdx.x * 256 + threadIdx.x;
    int v = (i < n) ? cnt[i] : 0;
    int tot; int e = block_exscan(v, tot) + boff[blockIdx.x];
    if (i < n) { offs[i] = e; cursor[i] = e; }
}

__global__ void scatter2_kernel(const int* __restrict__ s0, const int* __restrict__ d0,
                                const int* __restrict__ s1, const int* __restrict__ d1,
                                int* __restrict__ cursor0, int* __restrict__ srcidx0,
                                int* __restrict__ cursor1, int* __restrict__ srcidx1) {
    int i = blockIdx.x * blockDim.x + threadIdx.x;
    if (i < cE0) { int p = atomicAdd(&cursor0[d0[i]], 1); srcidx0[p] = s0[i]; }
    int j = i - cE0;
    if (j >= 0 && j < cE1) { int p = atomicAdd(&cursor1[d1[j]], 1); srcidx1[p] = s1[j]; }
}

// ---------------- weight transpose to bf16 ----------------
__global__ __launch_bounds__(256) void bf16_transpose2_kernel(const float* __restrict__ W1,
                                                              const float* __restrict__ W2,
                                                              short* __restrict__ bt1,
                                                              short* __restrict__ bt2) {
    int i = blockIdx.x * 256 + threadIdx.x;
    if (i < 256 * 256) {
        int k = i >> 8, n = i & 255;
        bt1[(size_t)n * 256 + k] = (short)f2bf(W1[i]);
    } else {
        int j = i - 256 * 256;
        if (j < 256 * 64) {
            int k = j >> 6, n = j & 63;
            bt2[(size_t)n * 256 + k] = (short)f2bf(W2[j]);
        }
    }
}

// ---------------- layer-0 GEMM: async-DMA staged, swizzled LDS (R5 verified) ----------------
__global__ __launch_bounds__(512, 4) void gemm0_deep(
    const float* __restrict__ A, const short* __restrict__ BT,
    unsigned short* __restrict__ C,
    const float* __restrict__ al, const float* __restrict__ ar,
    float* __restrict__ el, float* __restrict__ er,
    int M, int erN)
{
    constexpr int T = 8;                 // K=256 / BK=32
    constexpr int nh = 4;
    __shared__ float Asm[2][128 * 32];   // f32 tile, 128B rows, 8x16B chunks/row
    __shared__ short Bsm[2][256 * 32];   // bf16 tile, 64B rows, 4x16B chunks/row

    const int tid = threadIdx.x;
    const int w = tid >> 6;
    const int lane = tid & 63;
    const int ln = lane & 15;
    const int kg = lane >> 4;
    const int wr = w >> 2;               // 0..1
    const int wc = w & 3;                // 0..3
    const int m0 = blockIdx.x * 128;

    f32x4 acc[4][4];
    #pragma unroll
    for (int mi = 0; mi < 4; ++mi)
        #pragma unroll
        for (int ni = 0; ni < 4; ++ni)
            #pragma unroll
            for (int j = 0; j < 4; ++j) acc[mi][ni][j] = 0.f;

    auto stageA = [&](int k0, int b) {
        #pragma unroll
        for (int q = 0; q < 2; ++q) {
            int ci = w + q * 8;                       // 0..15
            int r = ci * 8 + (lane >> 3);             // 0..127
            int cl = (lane & 7) ^ (r & 7);            // logical chunk for this phys slot
            int gr = m0 + r; if (gr >= M) gr = M - 1; // clamp (dead rows discarded)
            gload_lds16(&A[(size_t)gr * 256 + k0 + cl * 4], &Asm[b][ci * 256]);
        }
    };
    auto stageB = [&](int k0, int b) {
        #pragma unroll
        for (int q = 0; q < 2; ++q) {
            int ci = w + q * 8;                       // 0..15
            int r = ci * 16 + (lane >> 2);            // 0..255
            int cl = (lane & 3) ^ ((r >> 1) & 3);
            gload_lds16(&BT[(size_t)r * 256 + k0 + cl * 8], &Bsm[b][ci * 512]);
        }
    };

    stageA(0, 0); stageB(0, 0);
    __syncthreads();

    const int swa = ln & 7;
    const int p0base = 2 * kg;           // logical A chunk pair (2kg, 2kg+1)
    const int pb = kg ^ ((ln >> 1) & 3); // B phys chunk

    int cur = 0;
    #pragma unroll
    for (int t = 0; t < T; ++t) {
        if (t + 1 < T) { stageA((t + 1) * 32, cur ^ 1); stageB((t + 1) * 32, cur ^ 1); }

        short8 af[4];
        {
            int pA = p0base ^ swa;
            #pragma unroll
            for (int mi = 0; mi < 4; ++mi) {
                int r = wr * 64 + mi * 16 + ln;
                const f32x4 q0 = *(const f32x4*)&Asm[cur][r * 32 + pA * 4];
                const f32x4 q1 = *(const f32x4*)&Asm[cur][r * 32 + (pA ^ 1) * 4];
                union { uint32_t u[4]; short8 s; } cv;
                cv.u[0] = cvtpk(q0[0], q0[1]);
                cv.u[1] = cvtpk(q0[2], q0[3]);
                cv.u[2] = cvtpk(q1[0], q1[1]);
                cv.u[3] = cvtpk(q1[2], q1[3]);
                af[mi] = cv.s;
            }
        }
        #pragma unroll
        for (int ni = 0; ni < 4; ++ni) {
            int rB = wc * 64 + ni * 16 + ln;
            short8 bf = *(const short8*)&Bsm[cur][rB * 32 + pb * 8];
            #pragma unroll
            for (int mi = 0; mi < 4; ++mi)
                acc[mi][ni] = __builtin_amdgcn_mfma_f32_16x16x32_bf16(af[mi], bf, acc[mi][ni], 0, 0, 0);
        }
        __syncthreads();
        cur ^= 1;
    }

    // epilogue: C store (bf16) + fused el/er (wave wc owns head h = wc)
    const int h = wc;
    float alv[4], arv[4];
    #pragma unroll
    for (int ni = 0; ni < 4; ++ni) {
        alv[ni] = al[h * 64 + ni * 16 + ln];
        arv[ni] = ar[h * 64 + ni * 16 + ln];
    }
    #pragma unroll
    for (int mi = 0; mi < 4; ++mi) {
        float pl[4] = {0, 0, 0, 0}, pr[4] = {0, 0, 0, 0};
        #pragma unroll
        for (int ni = 0; ni < 4; ++ni)
            #pragma unroll
            for (int j = 0; j < 4; ++j) {
                float v = acc[mi][ni][j];
                pl[j] += v * alv[ni];
                pr[j] += v * arv[ni];
            }
        #pragma unroll
        for (int j = 0; j < 4; ++j)
            #pragma unroll
            for (int o = 1; o < 16; o <<= 1) {
                pl[j] += __shfl_xor(pl[j], o);
                pr[j] += __shfl_xor(pr[j], o);
            }
        #pragma unroll
        for (int j = 0; j < 4; ++j) {
            int row = m0 + wr * 64 + mi * 16 + kg * 4 + j;
            if (row < M) {
                #pragma unroll
                for (int ni = 0; ni < 4; ++ni)
                    C[(size_t)row * 256 + wc * 64 + ni * 16 + ln] = f2bf(acc[mi][ni][j]);
                if (ln == 0) {
                    el[row * nh + h] = pl[j];
                    if (row < erN) er[row * nh + h] = pr[j];
                }
            }
        }
    }
}

// ---------------- agg0 with fused layer-1 projection (per-wave tail) ----------------
// One wave per dst node, 4 nodes/block (R11 structure). After the gather, the wave
// drops its h1 row into a 512B LDS slot and all 64 lanes compute one f2 column each
// (dot of the broadcast h1 row with W2T[lane] read from L2-hot global), then reduce
// el2/er2 across the wave. Deletes the separate gemm1 kernel + h1b round-trip.
__global__ __launch_bounds__(256) void agg0_kernel(
    const int* __restrict__ offs, const int* __restrict__ srcidx,
    const float* __restrict__ el, const float* __restrict__ er,
    const unsigned short* __restrict__ fb, const float* __restrict__ bias,
    const short* __restrict__ bt2,
    const float* __restrict__ al2, const float* __restrict__ ar2,
    unsigned short* __restrict__ f2b, float* __restrict__ el2, float* __restrict__ er2)
{
    __shared__ short h1s[4][256];   // per-wave h1 row (bf16)

    int w = threadIdx.x >> 6, lane = threadIdx.x & 63;
    int n = blockIdx.x * 4 + w;
    if (n >= cN1) return;
    int beg = offs[n], end = offs[n + 1];

    // ---- pass A: online max+sum, (16 sub-lanes) x (4 heads) ----
    int h4 = lane & 3, sub = lane >> 2;
    float erA = er[n * 4 + h4];
    float m = -1e30f, s = 0.f;
    for (int i = beg + sub; i < end; i += 16) {
        int sv = srcidx[i];
        float e = lrelu(el[sv * 4 + h4] + erA);
        if (e > m) { s = s * __expf(m - e) + 1.f; m = e; }
        else s += __expf(e - m);
    }
    #pragma unroll
    for (int o = 4; o < 64; o <<= 1) {
        float m2 = __shfl_xor(m, o), s2 = __shfl_xor(s, o);
        float M = fmaxf(m, m2);
        s = s * __expf(m - M) + s2 * __expf(m2 - M);
        m = M;
    }
    float inv = (s > 0.f) ? 1.f / s : 0.f;

    // ---- pass B: 4 edges/iter; 16 lanes x 32B cover the 512B row ----
    int q = lane >> 4, lcol = lane & 15;
    int hB = lcol >> 2;
    float mB = __shfl(m, hB);
    float invB = __shfl(inv, hB);
    float erB = __shfl(erA, hB);

    float a[16] = {};
    for (int i = beg + q; i < end; i += 4) {
        int sv = srcidx[i];
        float e = lrelu(el[sv * 4 + hB] + erB);
        float p = __expf(e - mB) * invB;
        const uint4* rp = (const uint4*)&fb[(size_t)sv * 256 + lcol * 16];
        uint4 v0 = rp[0];
        uint4 v1 = rp[1];
        a[0]  = fmaf(bf2f(v0.x & 0xffffu), p, a[0]);
        a[1]  = fmaf(bf2f(v0.x >> 16),     p, a[1]);
        a[2]  = fmaf(bf2f(v0.y & 0xffffu), p, a[2]);
        a[3]  = fmaf(bf2f(v0.y >> 16),     p, a[3]);
        a[4]  = fmaf(bf2f(v0.z & 0xffffu), p, a[4]);
        a[5]  = fmaf(bf2f(v0.z >> 16),     p, a[5]);
        a[6]  = fmaf(bf2f(v0.w & 0xffffu), p, a[6]);
        a[7]  = fmaf(bf2f(v0.w >> 16),     p, a[7]);
        a[8]  = fmaf(bf2f(v1.x & 0xffffu), p, a[8]);
        a[9]  = fmaf(bf2f(v1.x >> 16),     p, a[9]);
        a[10] = fmaf(bf2f(v1.y & 0xffffu), p, a[10]);
        a[11] = fmaf(bf2f(v1.y >> 16),     p, a[11]);
        a[12] = fmaf(bf2f(v1.z & 0xffffu), p, a[12]);
        a[13] = fmaf(bf2f(v1.z >> 16),     p, a[13]);
        a[14] = fmaf(bf2f(v1.w & 0xffffu), p, a[14]);
        a[15] = fmaf(bf2f(v1.w >> 16),     p, a[15]);
    }
    #pragma unroll
    for (int j = 0; j < 16; ++j) {
        a[j] += __shfl_xor(a[j], 16);
        a[j] += __shfl_xor(a[j], 32);
    }

    // relu + bias -> h1 row (bf16) into this wave's LDS slot (lanes 0..15)
    if (q == 0) {
        short8 r0, r1;
        #pragma unroll
        for (int j = 0; j < 8; ++j) {
            float o = a[j] + bias[lcol * 16 + j];
            r0[j] = (short)f2bf(o > 0.f ? o : 0.f);
        }
        #pragma unroll
        for (int j = 0; j < 8; ++j) {
            float o = a[8 + j] + bias[lcol * 16 + 8 + j];
            r1[j] = (short)f2bf(o > 0.f ? o : 0.f);
        }
        *(short8*)&h1s[w][lcol * 16] = r0;
        *(short8*)&h1s[w][lcol * 16 + 8] = r1;
    }
    // intra-wave LDS write->read ordering handled by compiler (same wave, may-alias)

    // ---- fused layer-1 projection: f2[n][lane] = h1_row . W2T[lane] ----
    float acc2 = 0.f;
    const short* wrow = &bt2[(size_t)lane * 256];
    #pragma unroll 8
    for (int kt = 0; kt < 32; ++kt) {
        short8 hv = *(const short8*)&h1s[w][kt * 8];       // broadcast read
        short8 wv = *(const short8*)&wrow[kt * 8];          // L2-hot global
        #pragma unroll
        for (int j = 0; j < 8; ++j)
            acc2 = fmaf(bf2f((uint32_t)(unsigned short)hv[j]),
                        bf2f((uint32_t)(unsigned short)wv[j]), acc2);
    }
    f2b[(size_t)n * 64 + lane] = f2bf(acc2);
    float pe = acc2 * al2[lane];
    float pr = acc2 * ar2[lane];
    #pragma unroll
    for (int o = 1; o < 64; o <<= 1) {
        pe += __shfl_xor(pe, o);
        pr += __shfl_xor(pr, o);
    }
    if (lane == 0) {
        el2[n] = pe;
        if (n < cN2) er2[n] = pr;
    }
}

// ---------------- layer-1 aggregation ----------------
__global__ __launch_bounds__(256) void agg1_kernel(const int* __restrict__ offs,
                                                   const int* __restrict__ srcidx,
                                                   const float* __restrict__ el,
                                                   const float* __restrict__ er,
                                                   const unsigned short* __restrict__ f2b,
                                                   const float* __restrict__ bias,
                                                   float* __restrict__ out) {
    int w = threadIdx.x >> 6, lane = threadIdx.x & 63;
    int n = blockIdx.x * 4 + w;
    if (n >= cN2) return;
    int beg = offs[n], end = offs[n + 1];
    float ern = er[n];

    float m = -1e30f, s = 0.f;
    for (int i = beg + lane; i < end; i += 64) {
        float e = lrelu(el[srcidx[i]] + ern);
        if (e > m) { s = s * __expf(m - e) + 1.f; m = e; }
        else s += __expf(e - m);
    }
    #pragma unroll
    for (int o = 1; o < 64; o <<= 1) {
        float m2 = __shfl_xor(m, o), s2 = __shfl_xor(s, o);
        float M = fmaxf(m, m2);
        s = s * __expf(m - M) + s2 * __expf(m2 - M);
        m = M;
    }
    float inv = (s > 0.f) ? 1.f / s : 0.f;

    int q = lane >> 3, lcol = lane & 7;
    float a[8] = {};
    for (int i = beg + q; i < end; i += 8) {
        int sv = srcidx[i];
        float e = lrelu(el[sv] + ern);
        float p = __expf(e - m) * inv;
        uint4 v = *(const uint4*)&f2b[(size_t)sv * 64 + lcol * 8];
        a[0] = fmaf(bf2f(v.x & 0xffffu), p, a[0]);
        a[1] = fmaf(bf2f(v.x >> 16),     p, a[1]);
        a[2] = fmaf(bf2f(v.y & 0xffffu), p, a[2]);
        a[3] = fmaf(bf2f(v.y >> 16),     p, a[3]);
        a[4] = fmaf(bf2f(v.z & 0xffffu), p, a[4]);
        a[5] = fmaf(bf2f(v.z >> 16),     p, a[5]);
        a[6] = fmaf(bf2f(v.w & 0xffffu), p, a[6]);
        a[7] = fmaf(bf2f(v.w >> 16),     p, a[7]);
    }
    #pragma unroll
    for (int j = 0; j < 8; ++j) {
        a[j] += __shfl_xor(a[j], 8);
        a[j] += __shfl_xor(a[j], 16);
        a[j] += __shfl_xor(a[j], 32);
    }
    if (q == 0) {
        float4 o0, o1;
        o0.x = a[0] + bias[lcol * 8 + 0];
        o0.y = a[1] + bias[lcol * 8 + 1];
        o0.z = a[2] + bias[lcol * 8 + 2];
        o0.w = a[3] + bias[lcol * 8 + 3];
        o1.x = a[4] + bias[lcol * 8 + 4];
        o1.y = a[5] + bias[lcol * 8 + 5];
        o1.z = a[6] + bias[lcol * 8 + 6];
        o1.w = a[7] + bias[lcol * 8 + 7];
        *(float4*)&out[(size_t)n * 64 + lcol * 8] = o0;
        *(float4*)&out[(size_t)n * 64 + lcol * 8 + 4] = o1;
    }
}

// ---------------- launch ----------------

extern "C" void kernel_launch(void* const* d_in, const int* in_sizes, int n_in,
                              void* d_out, int out_size, void* d_ws, size_t ws_size,
                              hipStream_t stream) {
    const float* x      = (const float*)d_in[0];
    const int*   e0_src = (const int*)d_in[1];
    const int*   e0_dst = (const int*)d_in[2];
    const int*   e1_src = (const int*)d_in[3];
    const int*   e1_dst = (const int*)d_in[4];
    const float* W1     = (const float*)d_in[5];
    const float* al1    = (const float*)d_in[6];
    const float* ar1    = (const float*)d_in[7];
    const float* b1     = (const float*)d_in[8];
    const float* W2     = (const float*)d_in[9];
    const float* al2    = (const float*)d_in[10];
    const float* ar2    = (const float*)d_in[11];
    const float* b2     = (const float*)d_in[12];
    float* out = (float*)d_out;

    char* ws = (char*)d_ws;
    size_t off = 0;
    auto alloc = [&](size_t bytes) -> void* {
        void* p = ws + off;
        off = (off + bytes + 255) & ~(size_t)255;
        return p;
    };
    unsigned short* fb  = (unsigned short*)alloc((size_t)cN0 * 256 * 2);
    unsigned short* f2b = (unsigned short*)alloc((size_t)cN1 * 64 * 2);
    float* el0  = (float*)alloc((size_t)cN0 * 4 * 4);
    float* er0  = (float*)alloc((size_t)cN1 * 4 * 4);
    float* el2  = (float*)alloc((size_t)cN1 * 4);
    float* er2  = (float*)alloc((size_t)cN2 * 4);
    short* bt1  = (short*)alloc((size_t)256 * 256 * 2);
    short* bt2  = (short*)alloc((size_t)64 * 256 * 2);
    int* cntB    = (int*)alloc((size_t)(cN1 + cN2) * 4);
    int* cnt0    = cntB;
    int* cnt1    = cntB + cN1;
    int* offs0   = (int*)alloc((size_t)(cN1 + 1) * 4);
    int* cursor0 = (int*)alloc((size_t)cN1 * 4);
    int* srcidx0 = (int*)alloc((size_t)cE0 * 4);
    int* offs1   = (int*)alloc((size_t)(cN2 + 1) * 4);
    int* cursor1 = (int*)alloc((size_t)cN2 * 4);
    int* srcidx1 = (int*)alloc((size_t)cE1 * 4);
    int* bsum0   = (int*)alloc(256 * 4);
    int* boff0   = (int*)alloc(256 * 4);
    int* bsum1   = (int*)alloc(256 * 4);
    int* boff1   = (int*)alloc(256 * 4);
    (void)ws_size; (void)n_in; (void)in_sizes; (void)out_size;

    const int nblk0 = (cN1 + 255) / 256;   // 196
    const int nblk1 = (cN2 + 255) / 256;   // 98

    hipMemsetAsync(cntB, 0, (size_t)(cN1 + cN2) * 4, stream);
    hist2_kernel<<<(cE0 + cE1 + 255) / 256, 256, 0, stream>>>(e0_dst, e1_dst, cnt0, cnt1);
    chunk_sum2_kernel<<<dim3(nblk0, 2), 256, 0, stream>>>(cnt0, cN1, cnt1, cN2, bsum0, bsum1, nblk1);
    top_scan2_kernel<<<1, 256, 0, stream>>>(bsum0, nblk0, bsum1, nblk1, boff0, boff1,
                                            offs0 + cN1, offs1 + cN2);
    chunk_scan2_kernel<<<dim3(nblk0, 2), 256, 0, stream>>>(cnt0, cN1, cnt1, cN2, boff0, boff1,
                                                           offs0, cursor0, offs1, cursor1, nblk1);
    scatter2_kernel<<<(cE0 + cE1 + 255) / 256, 256, 0, stream>>>(e0_src, e0_dst, e1_src, e1_dst,
                                                                 cursor0, srcidx0, cursor1, srcidx1);
    bf16_transpose2_kernel<<<(256 * 256 + 256 * 64 + 255) / 256, 256, 0, stream>>>(W1, W2, bt1, bt2);

    // ----- layer 0 -----
    gemm0_deep<<<(cN0 + 127) / 128, 512, 0, stream>>>(x, bt1, fb, al1, ar1, el0, er0, cN0, cN1);

    // ----- agg0 + fused layer-1 projection -----
    agg0_kernel<<<(cN1 + 3) / 4, 256, 0, stream>>>(offs0, srcidx0, el0, er0, fb, b1,
                                                   bt2, al2, ar2, f2b, el2, er2);

    // ----- layer 1 aggregation -----
    agg1_kernel<<<(cN2 + 3) / 4, 256, 0, stream>>>(offs1, srcidx1, el2, er2, f2b, b2, out);
}

// Round 14
// 180.683 us; speedup vs baseline: 1.8774x; 1.8774x over previous
//
#include <hip/hip_runtime.h>
#include <cstddef>
#include <cstdint>

constexpr int cN0 = 100000, cN1 = 50000, cN2 = 25000;
constexpr int cE0 = 400000, cE1 = 200000;
constexpr float SLOPE = 0.2f;

typedef short short8  __attribute__((ext_vector_type(8)));
typedef float f32x4   __attribute__((ext_vector_type(4)));

__device__ __forceinline__ unsigned short f2bf(float x) {
    union { float f; uint32_t u; } c; c.f = x;
    uint32_t u = c.u + 0x7FFFu + ((c.u >> 16) & 1u);   // RNE
    return (unsigned short)(u >> 16);
}
__device__ __forceinline__ float bf2f(uint32_t u) {
    union { uint32_t u; float f; } c; c.u = u << 16; return c.f;
}
__device__ __forceinline__ float lrelu(float x) { return x >= 0.f ? x : SLOPE * x; }

__device__ __forceinline__ uint32_t cvtpk(float lo, float hi) {
    uint32_t r;
    asm("v_cvt_pk_bf16_f32 %0, %1, %2" : "=v"(r) : "v"(lo), "v"(hi));
    return r;
}

// async global->LDS, 16B per lane; lds dst is wave-uniform base (HW adds lane*16)
__device__ __forceinline__ void gload_lds16(const void* g, void* l) {
    __builtin_amdgcn_global_load_lds(
        (const __attribute__((address_space(1))) unsigned int*)g,
        (__attribute__((address_space(3))) unsigned int*)l, 16, 0, 0);
}

// ---------------- CSR build (merged across both layers) ----------------

__global__ void hist2_kernel(const int* __restrict__ d0, const int* __restrict__ d1,
                             int* __restrict__ cnt0, int* __restrict__ cnt1) {
    int i = blockIdx.x * blockDim.x + threadIdx.x;
    if (i < cE0) atomicAdd(&cnt0[d0[i]], 1);
    int j = i - cE0;
    if (j >= 0 && j < cE1) atomicAdd(&cnt1[d1[j]], 1);
}

__global__ __launch_bounds__(256) void chunk_sum2_kernel(const int* __restrict__ cnt0, int n0,
                                                         const int* __restrict__ cnt1, int n1,
                                                         int* __restrict__ bsum0, int* __restrict__ bsum1,
                                                         int nblk1) {
    const int* cnt = blockIdx.y ? cnt1 : cnt0;
    int n = blockIdx.y ? n1 : n0;
    int* bsum = blockIdx.y ? bsum1 : bsum0;
    if (blockIdx.y && (int)blockIdx.x >= nblk1) return;
    int i = blockIdx.x * 256 + threadIdx.x;
    int v = (i < n) ? cnt[i] : 0;
    #pragma unroll
    for (int o = 32; o; o >>= 1) v += __shfl_xor(v, o);
    __shared__ int ws[4];
    if ((threadIdx.x & 63) == 0) ws[threadIdx.x >> 6] = v;
    __syncthreads();
    if (threadIdx.x == 0) bsum[blockIdx.x] = ws[0] + ws[1] + ws[2] + ws[3];
}

__device__ __forceinline__ int block_exscan(int v, int& total) {
    int lane = threadIdx.x & 63, w = threadIdx.x >> 6;
    int x = v;
    #pragma unroll
    for (int o = 1; o < 64; o <<= 1) { int t = __shfl_up(x, o); if (lane >= o) x += t; }
    __shared__ int ws[4];
    if (lane == 63) ws[w] = x;
    __syncthreads();
    int add = 0;
    #pragma unroll
    for (int i = 0; i < 4; ++i) if (i < w) add += ws[i];
    total = ws[0] + ws[1] + ws[2] + ws[3];
    return add + x - v;
}

__global__ __launch_bounds__(256) void top_scan2_kernel(const int* __restrict__ bsum0, int nblk0,
                                                        const int* __restrict__ bsum1, int nblk1,
                                                        int* __restrict__ boff0, int* __restrict__ boff1,
                                                        int* __restrict__ tot0, int* __restrict__ tot1) {
    int i = threadIdx.x;
    int tot;
    int v = (i < nblk0) ? bsum0[i] : 0;
    int e = block_exscan(v, tot);
    if (i < nblk0) boff0[i] = e;
    if (i == 0) *tot0 = tot;
    __syncthreads();
    v = (i < nblk1) ? bsum1[i] : 0;
    e = block_exscan(v, tot);
    if (i < nblk1) boff1[i] = e;
    if (i == 0) *tot1 = tot;
}

__global__ __launch_bounds__(256) void chunk_scan2_kernel(const int* __restrict__ cnt0, int n0,
                                                          const int* __restrict__ cnt1, int n1,
                                                          const int* __restrict__ boff0, const int* __restrict__ boff1,
                                                          int* __restrict__ offs0, int* __restrict__ cursor0,
                                                          int* __restrict__ offs1, int* __restrict__ cursor1,
                                                          int nblk1) {
    const int* cnt = blockIdx.y ? cnt1 : cnt0;
    const int* boff = blockIdx.y ? boff1 : boff0;
    int* offs = blockIdx.y ? offs1 : offs0;
    int* cursor = blockIdx.y ? cursor1 : cursor0;
    int n = blockIdx.y ? n1 : n0;
    if (blockIdx.y && (int)blockIdx.x >= nblk1) return;
    int i = blockIdx.x * 256 + threadIdx.x;
    int v = (i < n) ? cnt[i] : 0;
    int tot; int e = block_exscan(v, tot) + boff[blockIdx.x];
    if (i < n) { offs[i] = e; cursor[i] = e; }
}

__global__ void scatter2_kernel(const int* __restrict__ s0, const int* __restrict__ d0,
                                const int* __restrict__ s1, const int* __restrict__ d1,
                                int* __restrict__ cursor0, int* __restrict__ srcidx0,
                                int* __restrict__ cursor1, int* __restrict__ srcidx1) {
    int i = blockIdx.x * blockDim.x + threadIdx.x;
    if (i < cE0) { int p = atomicAdd(&cursor0[d0[i]], 1); srcidx0[p] = s0[i]; }
    int j = i - cE0;
    if (j >= 0 && j < cE1) { int p = atomicAdd(&cursor1[d1[j]], 1); srcidx1[p] = s1[j]; }
}

// ---------------- weight transpose to bf16 ----------------
__global__ __launch_bounds__(256) void bf16_transpose2_kernel(const float* __restrict__ W1,
                                                              const float* __restrict__ W2,
                                                              short* __restrict__ bt1,
                                                              short* __restrict__ bt2) {
    int i = blockIdx.x * 256 + threadIdx.x;
    if (i < 256 * 256) {
        int k = i >> 8, n = i & 255;
        bt1[(size_t)n * 256 + k] = (short)f2bf(W1[i]);
    } else {
        int j = i - 256 * 256;
        if (j < 256 * 64) {
            int k = j >> 6, n = j & 63;
            bt2[(size_t)n * 256 + k] = (short)f2bf(W2[j]);
        }
    }
}

// ---------------- layer-0 GEMM: async-DMA staged, swizzled LDS (R5 verified) ----------------
__global__ __launch_bounds__(512, 4) void gemm0_deep(
    const float* __restrict__ A, const short* __restrict__ BT,
    unsigned short* __restrict__ C,
    const float* __restrict__ al, const float* __restrict__ ar,
    float* __restrict__ el, float* __restrict__ er,
    int M, int erN)
{
    constexpr int T = 8;                 // K=256 / BK=32
    constexpr int nh = 4;
    __shared__ float Asm[2][128 * 32];   // f32 tile, 128B rows, 8x16B chunks/row
    __shared__ short Bsm[2][256 * 32];   // bf16 tile, 64B rows, 4x16B chunks/row

    const int tid = threadIdx.x;
    const int w = tid >> 6;
    const int lane = tid & 63;
    const int ln = lane & 15;
    const int kg = lane >> 4;
    const int wr = w >> 2;               // 0..1
    const int wc = w & 3;                // 0..3
    const int m0 = blockIdx.x * 128;

    f32x4 acc[4][4];
    #pragma unroll
    for (int mi = 0; mi < 4; ++mi)
        #pragma unroll
        for (int ni = 0; ni < 4; ++ni)
            #pragma unroll
            for (int j = 0; j < 4; ++j) acc[mi][ni][j] = 0.f;

    auto stageA = [&](int k0, int b) {
        #pragma unroll
        for (int q = 0; q < 2; ++q) {
            int ci = w + q * 8;                       // 0..15
            int r = ci * 8 + (lane >> 3);             // 0..127
            int cl = (lane & 7) ^ (r & 7);            // logical chunk for this phys slot
            int gr = m0 + r; if (gr >= M) gr = M - 1; // clamp (dead rows discarded)
            gload_lds16(&A[(size_t)gr * 256 + k0 + cl * 4], &Asm[b][ci * 256]);
        }
    };
    auto stageB = [&](int k0, int b) {
        #pragma unroll
        for (int q = 0; q < 2; ++q) {
            int ci = w + q * 8;                       // 0..15
            int r = ci * 16 + (lane >> 2);            // 0..255
            int cl = (lane & 3) ^ ((r >> 1) & 3);
            gload_lds16(&BT[(size_t)r * 256 + k0 + cl * 8], &Bsm[b][ci * 512]);
        }
    };

    stageA(0, 0); stageB(0, 0);
    __syncthreads();

    const int swa = ln & 7;
    const int p0base = 2 * kg;           // logical A chunk pair (2kg, 2kg+1)
    const int pb = kg ^ ((ln >> 1) & 3); // B phys chunk

    int cur = 0;
    #pragma unroll
    for (int t = 0; t < T; ++t) {
        if (t + 1 < T) { stageA((t + 1) * 32, cur ^ 1); stageB((t + 1) * 32, cur ^ 1); }

        short8 af[4];
        {
            int pA = p0base ^ swa;
            #pragma unroll
            for (int mi = 0; mi < 4; ++mi) {
                int r = wr * 64 + mi * 16 + ln;
                const f32x4 q0 = *(const f32x4*)&Asm[cur][r * 32 + pA * 4];
                const f32x4 q1 = *(const f32x4*)&Asm[cur][r * 32 + (pA ^ 1) * 4];
                union { uint32_t u[4]; short8 s; } cv;
                cv.u[0] = cvtpk(q0[0], q0[1]);
                cv.u[1] = cvtpk(q0[2], q0[3]);
                cv.u[2] = cvtpk(q1[0], q1[1]);
                cv.u[3] = cvtpk(q1[2], q1[3]);
                af[mi] = cv.s;
            }
        }
        #pragma unroll
        for (int ni = 0; ni < 4; ++ni) {
            int rB = wc * 64 + ni * 16 + ln;
            short8 bf = *(const short8*)&Bsm[cur][rB * 32 + pb * 8];
            #pragma unroll
            for (int mi = 0; mi < 4; ++mi)
                acc[mi][ni] = __builtin_amdgcn_mfma_f32_16x16x32_bf16(af[mi], bf, acc[mi][ni], 0, 0, 0);
        }
        __syncthreads();
        cur ^= 1;
    }

    // epilogue: C store (bf16) + fused el/er (wave wc owns head h = wc)
    const int h = wc;
    float alv[4], arv[4];
    #pragma unroll
    for (int ni = 0; ni < 4; ++ni) {
        alv[ni] = al[h * 64 + ni * 16 + ln];
        arv[ni] = ar[h * 64 + ni * 16 + ln];
    }
    #pragma unroll
    for (int mi = 0; mi < 4; ++mi) {
        float pl[4] = {0, 0, 0, 0}, pr[4] = {0, 0, 0, 0};
        #pragma unroll
        for (int ni = 0; ni < 4; ++ni)
            #pragma unroll
            for (int j = 0; j < 4; ++j) {
                float v = acc[mi][ni][j];
                pl[j] += v * alv[ni];
                pr[j] += v * arv[ni];
            }
        #pragma unroll
        for (int j = 0; j < 4; ++j)
            #pragma unroll
            for (int o = 1; o < 16; o <<= 1) {
                pl[j] += __shfl_xor(pl[j], o);
                pr[j] += __shfl_xor(pr[j], o);
            }
        #pragma unroll
        for (int j = 0; j < 4; ++j) {
            int row = m0 + wr * 64 + mi * 16 + kg * 4 + j;
            if (row < M) {
                #pragma unroll
                for (int ni = 0; ni < 4; ++ni)
                    C[(size_t)row * 256 + wc * 64 + ni * 16 + ln] = f2bf(acc[mi][ni][j]);
                if (ln == 0) {
                    el[row * nh + h] = pl[j];
                    if (row < erN) er[row * nh + h] = pr[j];
                }
            }
        }
    }
}

// ---------------- layer-1 GEMM (bf16 A) ----------------
template<int BM, int BN, int WR, int WC>
__global__ __launch_bounds__(256) void gemm_bf16_fused(
    const unsigned short* __restrict__ A, const short* __restrict__ BT,
    unsigned short* __restrict__ C,
    const float* __restrict__ al, const float* __restrict__ ar,
    float* __restrict__ el, float* __restrict__ er,
    int M, int K, int nh, int erN)
{
    constexpr int BK = 32;
    constexpr int PITCH = BK + 8;
    constexpr int MI = BM / WR / 16;
    constexpr int NI = BN / WC / 16;
    constexpr int AITB = BM * 4 / 256;
    constexpr int BIT  = BN * 4 / 256;

    __shared__ short As[BM * PITCH];
    __shared__ short Bs[BN * PITCH];

    const int tid = threadIdx.x;
    const int w = tid >> 6;
    const int lane = tid & 63;
    const int ln = lane & 15;
    const int kg = lane >> 4;
    const int wr = w / WC;
    const int wc = w % WC;
    const int m0 = blockIdx.x * BM;
    const int n0 = blockIdx.y * BN;
    const int N = nh * 64;

    f32x4 acc[MI][NI];
    #pragma unroll
    for (int mi = 0; mi < MI; ++mi)
        #pragma unroll
        for (int ni = 0; ni < NI; ++ni)
            #pragma unroll
            for (int j = 0; j < 4; ++j) acc[mi][ni][j] = 0.f;

    short8 aregb[AITB];
    short8 breg[BIT];

    auto loadA = [&](int k0) {
        #pragma unroll
        for (int p = 0; p < AITB; ++p) {
            int slot = tid + p * 256;
            int r = slot >> 2;
            int kq = (slot & 3) * 8;
            int gr = m0 + r;
            short8 v = {};
            if (gr < M) v = *(const short8*)&A[(size_t)gr * K + k0 + kq];
            aregb[p] = v;
        }
    };
    auto loadB = [&](int k0) {
        #pragma unroll
        for (int p = 0; p < BIT; ++p) {
            int slot = tid + p * 256;
            int r = slot >> 2;
            int kq = (slot & 3) * 8;
            breg[p] = *(const short8*)&BT[(size_t)(n0 + r) * K + k0 + kq];
        }
    };
    auto writeLDS = [&]() {
        #pragma unroll
        for (int p = 0; p < AITB; ++p) {
            int slot = tid + p * 256;
            int r = slot >> 2;
            int kq = (slot & 3) * 8;
            *(short8*)&As[r * PITCH + kq] = aregb[p];
        }
        #pragma unroll
        for (int p = 0; p < BIT; ++p) {
            int slot = tid + p * 256;
            int r = slot >> 2;
            int kq = (slot & 3) * 8;
            *(short8*)&Bs[r * PITCH + kq] = breg[p];
        }
    };

    loadA(0); loadB(0);
    const int T = K / BK;
    for (int t = 0; t < T; ++t) {
        writeLDS();
        __syncthreads();
        if (t + 1 < T) { loadA((t + 1) * BK); loadB((t + 1) * BK); }
        short8 af[MI], bf[NI];
        #pragma unroll
        for (int mi = 0; mi < MI; ++mi)
            af[mi] = *(const short8*)&As[(wr * MI * 16 + mi * 16 + ln) * PITCH + kg * 8];
        #pragma unroll
        for (int ni = 0; ni < NI; ++ni)
            bf[ni] = *(const short8*)&Bs[(wc * NI * 16 + ni * 16 + ln) * PITCH + kg * 8];
        #pragma unroll
        for (int mi = 0; mi < MI; ++mi)
            #pragma unroll
            for (int ni = 0; ni < NI; ++ni)
                acc[mi][ni] = __builtin_amdgcn_mfma_f32_16x16x32_bf16(af[mi], bf[ni], acc[mi][ni], 0, 0, 0);
        __syncthreads();
    }

    const int h = (n0 + wc * NI * 16) >> 6;
    float alv[NI], arv[NI];
    #pragma unroll
    for (int ni = 0; ni < NI; ++ni) {
        alv[ni] = al[h * 64 + ni * 16 + ln];
        arv[ni] = ar[h * 64 + ni * 16 + ln];
    }
    #pragma unroll
    for (int mi = 0; mi < MI; ++mi) {
        float pl[4] = {0, 0, 0, 0}, pr[4] = {0, 0, 0, 0};
        #pragma unroll
        for (int ni = 0; ni < NI; ++ni)
            #pragma unroll
            for (int j = 0; j < 4; ++j) {
                float v = acc[mi][ni][j];
                pl[j] += v * alv[ni];
                pr[j] += v * arv[ni];
            }
        #pragma unroll
        for (int j = 0; j < 4; ++j)
            #pragma unroll
            for (int o = 1; o < 16; o <<= 1) {
                pl[j] += __shfl_xor(pl[j], o);
                pr[j] += __shfl_xor(pr[j], o);
            }
        #pragma unroll
        for (int j = 0; j < 4; ++j) {
            int row = m0 + wr * MI * 16 + mi * 16 + kg * 4 + j;
            if (row < M) {
                #pragma unroll
                for (int ni = 0; ni < NI; ++ni)
                    C[(size_t)row * N + n0 + wc * NI * 16 + ni * 16 + ln] = f2bf(acc[mi][ni][j]);
                if (ln == 0) {
                    el[row * nh + h] = pl[j];
                    if (row < erN) er[row * nh + h] = pr[j];
                }
            }
        }
    }
}

// ---------------- aggregation ----------------

// layer0: one wave per dst node.
// Pass A: online max+sum, (16 sub-lanes) x (4 heads).
// Pass B: 4 edges/iter; 16 lanes x 32B cover the 512B row; cross-group combine.
__global__ __launch_bounds__(256) void agg0_kernel(const int* __restrict__ offs,
                                                   const int* __restrict__ srcidx,
                                                   const float* __restrict__ el,
                                                   const float* __restrict__ er,
                                                   const unsigned short* __restrict__ fb,
                                                   const float* __restrict__ bias,
                                                   unsigned short* __restrict__ h1b) {
    int w = threadIdx.x >> 6, lane = threadIdx.x & 63;
    int n = blockIdx.x * 4 + w;
    if (n >= cN1) return;
    int beg = offs[n], end = offs[n + 1];

    int h4 = lane & 3, sub = lane >> 2;
    float erA = er[n * 4 + h4];
    float m = -1e30f, s = 0.f;
    for (int i = beg + sub; i < end; i += 16) {
        int sv = srcidx[i];
        float e = lrelu(el[sv * 4 + h4] + erA);
        if (e > m) { s = s * __expf(m - e) + 1.f; m = e; }
        else s += __expf(e - m);
    }
    #pragma unroll
    for (int o = 4; o < 64; o <<= 1) {
        float m2 = __shfl_xor(m, o), s2 = __shfl_xor(s, o);
        float M = fmaxf(m, m2);
        s = s * __expf(m - M) + s2 * __expf(m2 - M);
        m = M;
    }
    float inv = (s > 0.f) ? 1.f / s : 0.f;

    int q = lane >> 4, lcol = lane & 15;
    int hB = lcol >> 2;
    float mB = __shfl(m, hB);
    float invB = __shfl(inv, hB);
    float erB = __shfl(erA, hB);

    float a[16] = {};
    for (int i = beg + q; i < end; i += 4) {
        int sv = srcidx[i];
        float e = lrelu(el[sv * 4 + hB] + erB);
        float p = __expf(e - mB) * invB;
        const uint4* rp = (const uint4*)&fb[(size_t)sv * 256 + lcol * 16];
        uint4 v0 = rp[0];
        uint4 v1 = rp[1];
        a[0]  = fmaf(bf2f(v0.x & 0xffffu), p, a[0]);
        a[1]  = fmaf(bf2f(v0.x >> 16),     p, a[1]);
        a[2]  = fmaf(bf2f(v0.y & 0xffffu), p, a[2]);
        a[3]  = fmaf(bf2f(v0.y >> 16),     p, a[3]);
        a[4]  = fmaf(bf2f(v0.z & 0xffffu), p, a[4]);
        a[5]  = fmaf(bf2f(v0.z >> 16),     p, a[5]);
        a[6]  = fmaf(bf2f(v0.w & 0xffffu), p, a[6]);
        a[7]  = fmaf(bf2f(v0.w >> 16),     p, a[7]);
        a[8]  = fmaf(bf2f(v1.x & 0xffffu), p, a[8]);
        a[9]  = fmaf(bf2f(v1.x >> 16),     p, a[9]);
        a[10] = fmaf(bf2f(v1.y & 0xffffu), p, a[10]);
        a[11] = fmaf(bf2f(v1.y >> 16),     p, a[11]);
        a[12] = fmaf(bf2f(v1.z & 0xffffu), p, a[12]);
        a[13] = fmaf(bf2f(v1.z >> 16),     p, a[13]);
        a[14] = fmaf(bf2f(v1.w & 0xffffu), p, a[14]);
        a[15] = fmaf(bf2f(v1.w >> 16),     p, a[15]);
    }
    #pragma unroll
    for (int j = 0; j < 16; ++j) {
        a[j] += __shfl_xor(a[j], 16);
        a[j] += __shfl_xor(a[j], 32);
    }
    if (q == 0) {
        short8 r0, r1;
        #pragma unroll
        for (int j = 0; j < 8; ++j) {
            float o = a[j] + bias[lcol * 16 + j];
            r0[j] = (short)f2bf(o > 0.f ? o : 0.f);
        }
        #pragma unroll
        for (int j = 0; j < 8; ++j) {
            float o = a[8 + j] + bias[lcol * 16 + 8 + j];
            r1[j] = (short)f2bf(o > 0.f ? o : 0.f);
        }
        *(short8*)&h1b[(size_t)n * 256 + lcol * 16] = r0;
        *(short8*)&h1b[(size_t)n * 256 + lcol * 16 + 8] = r1;
    }
}

// layer1: one wave per dst node; pass B: 8 edges/iter, 8 lanes x 16B cover the 128B row.
__global__ __launch_bounds__(256) void agg1_kernel(const int* __restrict__ offs,
                                                   const int* __restrict__ srcidx,
                                                   const float* __restrict__ el,
                                                   const float* __restrict__ er,
                                                   const unsigned short* __restrict__ f2b,
                                                   const float* __restrict__ bias,
                                                   float* __restrict__ out) {
    int w = threadIdx.x >> 6, lane = threadIdx.x & 63;
    int n = blockIdx.x * 4 + w;
    if (n >= cN2) return;
    int beg = offs[n], end = offs[n + 1];
    float ern = er[n];

    float m = -1e30f, s = 0.f;
    for (int i = beg + lane; i < end; i += 64) {
        float e = lrelu(el[srcidx[i]] + ern);
        if (e > m) { s = s * __expf(m - e) + 1.f; m = e; }
        else s += __expf(e - m);
    }
    #pragma unroll
    for (int o = 1; o < 64; o <<= 1) {
        float m2 = __shfl_xor(m, o), s2 = __shfl_xor(s, o);
        float M = fmaxf(m, m2);
        s = s * __expf(m - M) + s2 * __expf(m2 - M);
        m = M;
    }
    float inv = (s > 0.f) ? 1.f / s : 0.f;

    int q = lane >> 3, lcol = lane & 7;
    float a[8] = {};
    for (int i = beg + q; i < end; i += 8) {
        int sv = srcidx[i];
        float e = lrelu(el[sv] + ern);
        float p = __expf(e - m) * inv;
        uint4 v = *(const uint4*)&f2b[(size_t)sv * 64 + lcol * 8];
        a[0] = fmaf(bf2f(v.x & 0xffffu), p, a[0]);
        a[1] = fmaf(bf2f(v.x >> 16),     p, a[1]);
        a[2] = fmaf(bf2f(v.y & 0xffffu), p, a[2]);
        a[3] = fmaf(bf2f(v.y >> 16),     p, a[3]);
        a[4] = fmaf(bf2f(v.z & 0xffffu), p, a[4]);
        a[5] = fmaf(bf2f(v.z >> 16),     p, a[5]);
        a[6] = fmaf(bf2f(v.w & 0xffffu), p, a[6]);
        a[7] = fmaf(bf2f(v.w >> 16),     p, a[7]);
    }
    #pragma unroll
    for (int j = 0; j < 8; ++j) {
        a[j] += __shfl_xor(a[j], 8);
        a[j] += __shfl_xor(a[j], 16);
        a[j] += __shfl_xor(a[j], 32);
    }
    if (q == 0) {
        float4 o0, o1;
        o0.x = a[0] + bias[lcol * 8 + 0];
        o0.y = a[1] + bias[lcol * 8 + 1];
        o0.z = a[2] + bias[lcol * 8 + 2];
        o0.w = a[3] + bias[lcol * 8 + 3];
        o1.x = a[4] + bias[lcol * 8 + 4];
        o1.y = a[5] + bias[lcol * 8 + 5];
        o1.z = a[6] + bias[lcol * 8 + 6];
        o1.w = a[7] + bias[lcol * 8 + 7];
        *(float4*)&out[(size_t)n * 64 + lcol * 8] = o0;
        *(float4*)&out[(size_t)n * 64 + lcol * 8 + 4] = o1;
    }
}

// ---------------- launch ----------------

extern "C" void kernel_launch(void* const* d_in, const int* in_sizes, int n_in,
                              void* d_out, int out_size, void* d_ws, size_t ws_size,
                              hipStream_t stream) {
    const float* x      = (const float*)d_in[0];
    const int*   e0_src = (const int*)d_in[1];
    const int*   e0_dst = (const int*)d_in[2];
    const int*   e1_src = (const int*)d_in[3];
    const int*   e1_dst = (const int*)d_in[4];
    const float* W1     = (const float*)d_in[5];
    const float* al1    = (const float*)d_in[6];
    const float* ar1    = (const float*)d_in[7];
    const float* b1     = (const float*)d_in[8];
    const float* W2     = (const float*)d_in[9];
    const float* al2    = (const float*)d_in[10];
    const float* ar2    = (const float*)d_in[11];
    const float* b2     = (const float*)d_in[12];
    float* out = (float*)d_out;

    char* ws = (char*)d_ws;
    size_t off = 0;
    auto alloc = [&](size_t bytes) -> void* {
        void* p = ws + off;
        off = (off + bytes + 255) & ~(size_t)255;
        return p;
    };
    unsigned short* fb  = (unsigned short*)alloc((size_t)cN0 * 256 * 2);
    unsigned short* h1b = (unsigned short*)alloc((size_t)cN1 * 256 * 2);
    unsigned short* f2b = (unsigned short*)alloc((size_t)cN1 * 64 * 2);
    float* el0  = (float*)alloc((size_t)cN0 * 4 * 4);
    float* er0  = (float*)alloc((size_t)cN1 * 4 * 4);
    float* el2  = (float*)alloc((size_t)cN1 * 4);
    float* er2  = (float*)alloc((size_t)cN2 * 4);
    short* bt1  = (short*)alloc((size_t)256 * 256 * 2);
    short* bt2  = (short*)alloc((size_t)64 * 256 * 2);
    int* cntB    = (int*)alloc((size_t)(cN1 + cN2) * 4);
    int* cnt0    = cntB;
    int* cnt1    = cntB + cN1;
    int* offs0   = (int*)alloc((size_t)(cN1 + 1) * 4);
    int* cursor0 = (int*)alloc((size_t)cN1 * 4);
    int* srcidx0 = (int*)alloc((size_t)cE0 * 4);
    int* offs1   = (int*)alloc((size_t)(cN2 + 1) * 4);
    int* cursor1 = (int*)alloc((size_t)cN2 * 4);
    int* srcidx1 = (int*)alloc((size_t)cE1 * 4);
    int* bsum0   = (int*)alloc(256 * 4);
    int* boff0   = (int*)alloc(256 * 4);
    int* bsum1   = (int*)alloc(256 * 4);
    int* boff1   = (int*)alloc(256 * 4);
    (void)ws_size; (void)n_in; (void)in_sizes; (void)out_size;

    const int nblk0 = (cN1 + 255) / 256;   // 196
    const int nblk1 = (cN2 + 255) / 256;   // 98

    hipMemsetAsync(cntB, 0, (size_t)(cN1 + cN2) * 4, stream);
    hist2_kernel<<<(cE0 + cE1 + 255) / 256, 256, 0, stream>>>(e0_dst, e1_dst, cnt0, cnt1);
    chunk_sum2_kernel<<<dim3(nblk0, 2), 256, 0, stream>>>(cnt0, cN1, cnt1, cN2, bsum0, bsum1, nblk1);
    top_scan2_kernel<<<1, 256, 0, stream>>>(bsum0, nblk0, bsum1, nblk1, boff0, boff1,
                                            offs0 + cN1, offs1 + cN2);
    chunk_scan2_kernel<<<dim3(nblk0, 2), 256, 0, stream>>>(cnt0, cN1, cnt1, cN2, boff0, boff1,
                                                           offs0, cursor0, offs1, cursor1, nblk1);
    scatter2_kernel<<<(cE0 + cE1 + 255) / 256, 256, 0, stream>>>(e0_src, e0_dst, e1_src, e1_dst,
                                                                 cursor0, srcidx0, cursor1, srcidx1);
    bf16_transpose2_kernel<<<(256 * 256 + 256 * 64 + 255) / 256, 256, 0, stream>>>(W1, W2, bt1, bt2);

    // ----- layer 0 -----
    gemm0_deep<<<(cN0 + 127) / 128, 512, 0, stream>>>(x, bt1, fb, al1, ar1, el0, er0, cN0, cN1);
    agg0_kernel<<<(cN1 + 3) / 4, 256, 0, stream>>>(offs0, srcidx0, el0, er0, fb, b1, h1b);

    // ----- layer 1 -----
    gemm_bf16_fused<128, 64, 4, 1><<<dim3((cN1 + 127) / 128, 1), 256, 0, stream>>>(
        h1b, bt2, f2b, al2, ar2, el2, er2, cN1, 256, 1, cN2);
    agg1_kernel<<<(cN2 + 3) / 4, 256, 0, stream>>>(offs1, srcidx1, el2, er2, f2b, b2, out);
}

// Round 15
// 176.809 us; speedup vs baseline: 1.9185x; 1.0219x over previous
//
#include <hip/hip_runtime.h>
#include <cstddef>
#include <cstdint>

constexpr int cN0 = 100000, cN1 = 50000, cN2 = 25000;
constexpr int cE0 = 400000, cE1 = 200000;
constexpr float SLOPE = 0.2f;

typedef short short8  __attribute__((ext_vector_type(8)));
typedef float f32x4   __attribute__((ext_vector_type(4)));

__device__ __forceinline__ unsigned short f2bf(float x) {
    union { float f; uint32_t u; } c; c.f = x;
    uint32_t u = c.u + 0x7FFFu + ((c.u >> 16) & 1u);   // RNE
    return (unsigned short)(u >> 16);
}
__device__ __forceinline__ float bf2f(uint32_t u) {
    union { uint32_t u; float f; } c; c.u = u << 16; return c.f;
}
__device__ __forceinline__ float lrelu(float x) { return x >= 0.f ? x : SLOPE * x; }

__device__ __forceinline__ uint32_t cvtpk(float lo, float hi) {
    uint32_t r;
    asm("v_cvt_pk_bf16_f32 %0, %1, %2" : "=v"(r) : "v"(lo), "v"(hi));
    return r;
}

// async global->LDS, 16B per lane; lds dst is wave-uniform base (HW adds lane*16)
__device__ __forceinline__ void gload_lds16(const void* g, void* l) {
    __builtin_amdgcn_global_load_lds(
        (const __attribute__((address_space(1))) unsigned int*)g,
        (__attribute__((address_space(3))) unsigned int*)l, 16, 0, 0);
}

// ---------------- CSR build (merged across both layers) + weight transpose ----------------

// hist for both edge lists + bf16 weight transpose folded into the same launch
__global__ void hist2t_kernel(const int* __restrict__ d0, const int* __restrict__ d1,
                              int* __restrict__ cnt0, int* __restrict__ cnt1,
                              const float* __restrict__ W1, const float* __restrict__ W2,
                              short* __restrict__ bt1, short* __restrict__ bt2) {
    int i = blockIdx.x * blockDim.x + threadIdx.x;
    if (i < cE0) atomicAdd(&cnt0[d0[i]], 1);
    int j = i - cE0;
    if (j >= 0 && j < cE1) atomicAdd(&cnt1[d1[j]], 1);
    // transpose work rides along in the first 320 blocks
    if (i < 256 * 256) {
        int k = i >> 8, n = i & 255;
        bt1[(size_t)n * 256 + k] = (short)f2bf(W1[i]);
    } else {
        int jj = i - 256 * 256;
        if (jj < 256 * 64) {
            int k = jj >> 6, n = jj & 63;
            bt2[(size_t)n * 256 + k] = (short)f2bf(W2[jj]);
        }
    }
}

__global__ __launch_bounds__(256) void chunk_sum2_kernel(const int* __restrict__ cnt0, int n0,
                                                         const int* __restrict__ cnt1, int n1,
                                                         int* __restrict__ bsum0, int* __restrict__ bsum1,
                                                         int nblk1) {
    const int* cnt = blockIdx.y ? cnt1 : cnt0;
    int n = blockIdx.y ? n1 : n0;
    int* bsum = blockIdx.y ? bsum1 : bsum0;
    if (blockIdx.y && (int)blockIdx.x >= nblk1) return;
    int i = blockIdx.x * 256 + threadIdx.x;
    int v = (i < n) ? cnt[i] : 0;
    #pragma unroll
    for (int o = 32; o; o >>= 1) v += __shfl_xor(v, o);
    __shared__ int ws[4];
    if ((threadIdx.x & 63) == 0) ws[threadIdx.x >> 6] = v;
    __syncthreads();
    if (threadIdx.x == 0) bsum[blockIdx.x] = ws[0] + ws[1] + ws[2] + ws[3];
}

__device__ __forceinline__ int block_exscan(int v, int& total) {
    int lane = threadIdx.x & 63, w = threadIdx.x >> 6;
    int x = v;
    #pragma unroll
    for (int o = 1; o < 64; o <<= 1) { int t = __shfl_up(x, o); if (lane >= o) x += t; }
    __shared__ int ws[4];
    if (lane == 63) ws[w] = x;
    __syncthreads();
    int add = 0;
    #pragma unroll
    for (int i = 0; i < 4; ++i) if (i < w) add += ws[i];
    total = ws[0] + ws[1] + ws[2] + ws[3];
    return add + x - v;
}

// chunk scan with inlined top-level scan: each block locally reduces bsum[0..blockIdx.x)
// (nblk <= 256 -> one value per thread). Totals are compile-time constants (cE0/cE1).
__global__ __launch_bounds__(256) void chunk_scan2b_kernel(const int* __restrict__ cnt0, int n0,
                                                           const int* __restrict__ cnt1, int n1,
                                                           const int* __restrict__ bsum0,
                                                           const int* __restrict__ bsum1,
                                                           int* __restrict__ offs0, int* __restrict__ cursor0,
                                                           int* __restrict__ offs1, int* __restrict__ cursor1,
                                                           int nblk1) {
    const int* cnt  = blockIdx.y ? cnt1 : cnt0;
    const int* bsum = blockIdx.y ? bsum1 : bsum0;
    int* offs   = blockIdx.y ? offs1 : offs0;
    int* cursor = blockIdx.y ? cursor1 : cursor0;
    int n = blockIdx.y ? n1 : n0;
    if (blockIdx.y && (int)blockIdx.x >= nblk1) return;

    if (blockIdx.x == 0 && threadIdx.x == 0) offs[n] = blockIdx.y ? cE1 : cE0;

    // local top-scan: boff = sum(bsum[0..blockIdx.x))
    __shared__ int boff_s;
    {
        int bv = ((int)threadIdx.x < (int)blockIdx.x) ? bsum[threadIdx.x] : 0;
        #pragma unroll
        for (int o = 32; o; o >>= 1) bv += __shfl_xor(bv, o);
        __shared__ int ws2[4];
        if ((threadIdx.x & 63) == 0) ws2[threadIdx.x >> 6] = bv;
        __syncthreads();
        if (threadIdx.x == 0) boff_s = ws2[0] + ws2[1] + ws2[2] + ws2[3];
        __syncthreads();
    }
    int boff = boff_s;

    int i = blockIdx.x * 256 + threadIdx.x;
    int v = (i < n) ? cnt[i] : 0;
    int tot; int e = block_exscan(v, tot) + boff;
    if (i < n) { offs[i] = e; cursor[i] = e; }
}

__global__ void scatter2_kernel(const int* __restrict__ s0, const int* __restrict__ d0,
                                const int* __restrict__ s1, const int* __restrict__ d1,
                                int* __restrict__ cursor0, int* __restrict__ srcidx0,
                                int* __restrict__ cursor1, int* __restrict__ srcidx1) {
    int i = blockIdx.x * blockDim.x + threadIdx.x;
    if (i < cE0) { int p = atomicAdd(&cursor0[d0[i]], 1); srcidx0[p] = s0[i]; }
    int j = i - cE0;
    if (j >= 0 && j < cE1) { int p = atomicAdd(&cursor1[d1[j]], 1); srcidx1[p] = s1[j]; }
}

// ---------------- layer-0 GEMM: async-DMA staged, swizzled LDS (R5 verified) ----------------
__global__ __launch_bounds__(512, 4) void gemm0_deep(
    const float* __restrict__ A, const short* __restrict__ BT,
    unsigned short* __restrict__ C,
    const float* __restrict__ al, const float* __restrict__ ar,
    float* __restrict__ el, float* __restrict__ er,
    int M, int erN)
{
    constexpr int T = 8;                 // K=256 / BK=32
    constexpr int nh = 4;
    __shared__ float Asm[2][128 * 32];   // f32 tile, 128B rows, 8x16B chunks/row
    __shared__ short Bsm[2][256 * 32];   // bf16 tile, 64B rows, 4x16B chunks/row

    const int tid = threadIdx.x;
    const int w = tid >> 6;
    const int lane = tid & 63;
    const int ln = lane & 15;
    const int kg = lane >> 4;
    const int wr = w >> 2;               // 0..1
    const int wc = w & 3;                // 0..3
    const int m0 = blockIdx.x * 128;

    f32x4 acc[4][4];
    #pragma unroll
    for (int mi = 0; mi < 4; ++mi)
        #pragma unroll
        for (int ni = 0; ni < 4; ++ni)
            #pragma unroll
            for (int j = 0; j < 4; ++j) acc[mi][ni][j] = 0.f;

    auto stageA = [&](int k0, int b) {
        #pragma unroll
        for (int q = 0; q < 2; ++q) {
            int ci = w + q * 8;                       // 0..15
            int r = ci * 8 + (lane >> 3);             // 0..127
            int cl = (lane & 7) ^ (r & 7);            // logical chunk for this phys slot
            int gr = m0 + r; if (gr >= M) gr = M - 1; // clamp (dead rows discarded)
            gload_lds16(&A[(size_t)gr * 256 + k0 + cl * 4], &Asm[b][ci * 256]);
        }
    };
    auto stageB = [&](int k0, int b) {
        #pragma unroll
        for (int q = 0; q < 2; ++q) {
            int ci = w + q * 8;                       // 0..15
            int r = ci * 16 + (lane >> 2);            // 0..255
            int cl = (lane & 3) ^ ((r >> 1) & 3);
            gload_lds16(&BT[(size_t)r * 256 + k0 + cl * 8], &Bsm[b][ci * 512]);
        }
    };

    stageA(0, 0); stageB(0, 0);
    __syncthreads();

    const int swa = ln & 7;
    const int p0base = 2 * kg;           // logical A chunk pair (2kg, 2kg+1)
    const int pb = kg ^ ((ln >> 1) & 3); // B phys chunk

    int cur = 0;
    #pragma unroll
    for (int t = 0; t < T; ++t) {
        if (t + 1 < T) { stageA((t + 1) * 32, cur ^ 1); stageB((t + 1) * 32, cur ^ 1); }

        short8 af[4];
        {
            int pA = p0base ^ swa;
            #pragma unroll
            for (int mi = 0; mi < 4; ++mi) {
                int r = wr * 64 + mi * 16 + ln;
                const f32x4 q0 = *(const f32x4*)&Asm[cur][r * 32 + pA * 4];
                const f32x4 q1 = *(const f32x4*)&Asm[cur][r * 32 + (pA ^ 1) * 4];
                union { uint32_t u[4]; short8 s; } cv;
                cv.u[0] = cvtpk(q0[0], q0[1]);
                cv.u[1] = cvtpk(q0[2], q0[3]);
                cv.u[2] = cvtpk(q1[0], q1[1]);
                cv.u[3] = cvtpk(q1[2], q1[3]);
                af[mi] = cv.s;
            }
        }
        #pragma unroll
        for (int ni = 0; ni < 4; ++ni) {
            int rB = wc * 64 + ni * 16 + ln;
            short8 bf = *(const short8*)&Bsm[cur][rB * 32 + pb * 8];
            #pragma unroll
            for (int mi = 0; mi < 4; ++mi)
                acc[mi][ni] = __builtin_amdgcn_mfma_f32_16x16x32_bf16(af[mi], bf, acc[mi][ni], 0, 0, 0);
        }
        __syncthreads();
        cur ^= 1;
    }

    // epilogue: C store (bf16) + fused el/er (wave wc owns head h = wc)
    const int h = wc;
    float alv[4], arv[4];
    #pragma unroll
    for (int ni = 0; ni < 4; ++ni) {
        alv[ni] = al[h * 64 + ni * 16 + ln];
        arv[ni] = ar[h * 64 + ni * 16 + ln];
    }
    #pragma unroll
    for (int mi = 0; mi < 4; ++mi) {
        float pl[4] = {0, 0, 0, 0}, pr[4] = {0, 0, 0, 0};
        #pragma unroll
        for (int ni = 0; ni < 4; ++ni)
            #pragma unroll
            for (int j = 0; j < 4; ++j) {
                float v = acc[mi][ni][j];
                pl[j] += v * alv[ni];
                pr[j] += v * arv[ni];
            }
        #pragma unroll
        for (int j = 0; j < 4; ++j)
            #pragma unroll
            for (int o = 1; o < 16; o <<= 1) {
                pl[j] += __shfl_xor(pl[j], o);
                pr[j] += __shfl_xor(pr[j], o);
            }
        #pragma unroll
        for (int j = 0; j < 4; ++j) {
            int row = m0 + wr * 64 + mi * 16 + kg * 4 + j;
            if (row < M) {
                #pragma unroll
                for (int ni = 0; ni < 4; ++ni)
                    C[(size_t)row * 256 + wc * 64 + ni * 16 + ln] = f2bf(acc[mi][ni][j]);
                if (ln == 0) {
                    el[row * nh + h] = pl[j];
                    if (row < erN) er[row * nh + h] = pr[j];
                }
            }
        }
    }
}

// ---------------- layer-1 GEMM (bf16 A) ----------------
template<int BM, int BN, int WR, int WC>
__global__ __launch_bounds__(256) void gemm_bf16_fused(
    const unsigned short* __restrict__ A, const short* __restrict__ BT,
    unsigned short* __restrict__ C,
    const float* __restrict__ al, const float* __restrict__ ar,
    float* __restrict__ el, float* __restrict__ er,
    int M, int K, int nh, int erN)
{
    constexpr int BK = 32;
    constexpr int PITCH = BK + 8;
    constexpr int MI = BM / WR / 16;
    constexpr int NI = BN / WC / 16;
    constexpr int AITB = BM * 4 / 256;
    constexpr int BIT  = BN * 4 / 256;

    __shared__ short As[BM * PITCH];
    __shared__ short Bs[BN * PITCH];

    const int tid = threadIdx.x;
    const int w = tid >> 6;
    const int lane = tid & 63;
    const int ln = lane & 15;
    const int kg = lane >> 4;
    const int wr = w / WC;
    const int wc = w % WC;
    const int m0 = blockIdx.x * BM;
    const int n0 = blockIdx.y * BN;
    const int N = nh * 64;

    f32x4 acc[MI][NI];
    #pragma unroll
    for (int mi = 0; mi < MI; ++mi)
        #pragma unroll
        for (int ni = 0; ni < NI; ++ni)
            #pragma unroll
            for (int j = 0; j < 4; ++j) acc[mi][ni][j] = 0.f;

    short8 aregb[AITB];
    short8 breg[BIT];

    auto loadA = [&](int k0) {
        #pragma unroll
        for (int p = 0; p < AITB; ++p) {
            int slot = tid + p * 256;
            int r = slot >> 2;
            int kq = (slot & 3) * 8;
            int gr = m0 + r;
            short8 v = {};
            if (gr < M) v = *(const short8*)&A[(size_t)gr * K + k0 + kq];
            aregb[p] = v;
        }
    };
    auto loadB = [&](int k0) {
        #pragma unroll
        for (int p = 0; p < BIT; ++p) {
            int slot = tid + p * 256;
            int r = slot >> 2;
            int kq = (slot & 3) * 8;
            breg[p] = *(const short8*)&BT[(size_t)(n0 + r) * K + k0 + kq];
        }
    };
    auto writeLDS = [&]() {
        #pragma unroll
        for (int p = 0; p < AITB; ++p) {
            int slot = tid + p * 256;
            int r = slot >> 2;
            int kq = (slot & 3) * 8;
            *(short8*)&As[r * PITCH + kq] = aregb[p];
        }
        #pragma unroll
        for (int p = 0; p < BIT; ++p) {
            int slot = tid + p * 256;
            int r = slot >> 2;
            int kq = (slot & 3) * 8;
            *(short8*)&Bs[r * PITCH + kq] = breg[p];
        }
    };

    loadA(0); loadB(0);
    const int T = K / BK;
    for (int t = 0; t < T; ++t) {
        writeLDS();
        __syncthreads();
        if (t + 1 < T) { loadA((t + 1) * BK); loadB((t + 1) * BK); }
        short8 af[MI], bf[NI];
        #pragma unroll
        for (int mi = 0; mi < MI; ++mi)
            af[mi] = *(const short8*)&As[(wr * MI * 16 + mi * 16 + ln) * PITCH + kg * 8];
        #pragma unroll
        for (int ni = 0; ni < NI; ++ni)
            bf[ni] = *(const short8*)&Bs[(wc * NI * 16 + ni * 16 + ln) * PITCH + kg * 8];
        #pragma unroll
        for (int mi = 0; mi < MI; ++mi)
            #pragma unroll
            for (int ni = 0; ni < NI; ++ni)
                acc[mi][ni] = __builtin_amdgcn_mfma_f32_16x16x32_bf16(af[mi], bf[ni], acc[mi][ni], 0, 0, 0);
        __syncthreads();
    }

    const int h = (n0 + wc * NI * 16) >> 6;
    float alv[NI], arv[NI];
    #pragma unroll
    for (int ni = 0; ni < NI; ++ni) {
        alv[ni] = al[h * 64 + ni * 16 + ln];
        arv[ni] = ar[h * 64 + ni * 16 + ln];
    }
    #pragma unroll
    for (int mi = 0; mi < MI; ++mi) {
        float pl[4] = {0, 0, 0, 0}, pr[4] = {0, 0, 0, 0};
        #pragma unroll
        for (int ni = 0; ni < NI; ++ni)
            #pragma unroll
            for (int j = 0; j < 4; ++j) {
                float v = acc[mi][ni][j];
                pl[j] += v * alv[ni];
                pr[j] += v * arv[ni];
            }
        #pragma unroll
        for (int j = 0; j < 4; ++j)
            #pragma unroll
            for (int o = 1; o < 16; o <<= 1) {
                pl[j] += __shfl_xor(pl[j], o);
                pr[j] += __shfl_xor(pr[j], o);
            }
        #pragma unroll
        for (int j = 0; j < 4; ++j) {
            int row = m0 + wr * MI * 16 + mi * 16 + kg * 4 + j;
            if (row < M) {
                #pragma unroll
                for (int ni = 0; ni < NI; ++ni)
                    C[(size_t)row * N + n0 + wc * NI * 16 + ni * 16 + ln] = f2bf(acc[mi][ni][j]);
                if (ln == 0) {
                    el[row * nh + h] = pl[j];
                    if (row < erN) er[row * nh + h] = pr[j];
                }
            }
        }
    }
}

// ---------------- aggregation ----------------

// layer0: one wave per dst node.
__global__ __launch_bounds__(256) void agg0_kernel(const int* __restrict__ offs,
                                                   const int* __restrict__ srcidx,
                                                   const float* __restrict__ el,
                                                   const float* __restrict__ er,
                                                   const unsigned short* __restrict__ fb,
                                                   const float* __restrict__ bias,
                                                   unsigned short* __restrict__ h1b) {
    int w = threadIdx.x >> 6, lane = threadIdx.x & 63;
    int n = blockIdx.x * 4 + w;
    if (n >= cN1) return;
    int beg = offs[n], end = offs[n + 1];

    int h4 = lane & 3, sub = lane >> 2;
    float erA = er[n * 4 + h4];
    float m = -1e30f, s = 0.f;
    for (int i = beg + sub; i < end; i += 16) {
        int sv = srcidx[i];
        float e = lrelu(el[sv * 4 + h4] + erA);
        if (e > m) { s = s * __expf(m - e) + 1.f; m = e; }
        else s += __expf(e - m);
    }
    #pragma unroll
    for (int o = 4; o < 64; o <<= 1) {
        float m2 = __shfl_xor(m, o), s2 = __shfl_xor(s, o);
        float M = fmaxf(m, m2);
        s = s * __expf(m - M) + s2 * __expf(m2 - M);
        m = M;
    }
    float inv = (s > 0.f) ? 1.f / s : 0.f;

    int q = lane >> 4, lcol = lane & 15;
    int hB = lcol >> 2;
    float mB = __shfl(m, hB);
    float invB = __shfl(inv, hB);
    float erB = __shfl(erA, hB);

    float a[16] = {};
    for (int i = beg + q; i < end; i += 4) {
        int sv = srcidx[i];
        float e = lrelu(el[sv * 4 + hB] + erB);
        float p = __expf(e - mB) * invB;
        const uint4* rp = (const uint4*)&fb[(size_t)sv * 256 + lcol * 16];
        uint4 v0 = rp[0];
        uint4 v1 = rp[1];
        a[0]  = fmaf(bf2f(v0.x & 0xffffu), p, a[0]);
        a[1]  = fmaf(bf2f(v0.x >> 16),     p, a[1]);
        a[2]  = fmaf(bf2f(v0.y & 0xffffu), p, a[2]);
        a[3]  = fmaf(bf2f(v0.y >> 16),     p, a[3]);
        a[4]  = fmaf(bf2f(v0.z & 0xffffu), p, a[4]);
        a[5]  = fmaf(bf2f(v0.z >> 16),     p, a[5]);
        a[6]  = fmaf(bf2f(v0.w & 0xffffu), p, a[6]);
        a[7]  = fmaf(bf2f(v0.w >> 16),     p, a[7]);
        a[8]  = fmaf(bf2f(v1.x & 0xffffu), p, a[8]);
        a[9]  = fmaf(bf2f(v1.x >> 16),     p, a[9]);
        a[10] = fmaf(bf2f(v1.y & 0xffffu), p, a[10]);
        a[11] = fmaf(bf2f(v1.y >> 16),     p, a[11]);
        a[12] = fmaf(bf2f(v1.z & 0xffffu), p, a[12]);
        a[13] = fmaf(bf2f(v1.z >> 16),     p, a[13]);
        a[14] = fmaf(bf2f(v1.w & 0xffffu), p, a[14]);
        a[15] = fmaf(bf2f(v1.w >> 16),     p, a[15]);
    }
    #pragma unroll
    for (int j = 0; j < 16; ++j) {
        a[j] += __shfl_xor(a[j], 16);
        a[j] += __shfl_xor(a[j], 32);
    }
    if (q == 0) {
        short8 r0, r1;
        #pragma unroll
        for (int j = 0; j < 8; ++j) {
            float o = a[j] + bias[lcol * 16 + j];
            r0[j] = (short)f2bf(o > 0.f ? o : 0.f);
        }
        #pragma unroll
        for (int j = 0; j < 8; ++j) {
            float o = a[8 + j] + bias[lcol * 16 + 8 + j];
            r1[j] = (short)f2bf(o > 0.f ? o : 0.f);
        }
        *(short8*)&h1b[(size_t)n * 256 + lcol * 16] = r0;
        *(short8*)&h1b[(size_t)n * 256 + lcol * 16 + 8] = r1;
    }
}

// layer1: one wave per dst node; pass B: 8 edges/iter.
__global__ __launch_bounds__(256) void agg1_kernel(const int* __restrict__ offs,
                                                   const int* __restrict__ srcidx,
                                                   const float* __restrict__ el,
                                                   const float* __restrict__ er,
                                                   const unsigned short* __restrict__ f2b,
                                                   const float* __restrict__ bias,
                                                   float* __restrict__ out) {
    int w = threadIdx.x >> 6, lane = threadIdx.x & 63;
    int n = blockIdx.x * 4 + w;
    if (n >= cN2) return;
    int beg = offs[n], end = offs[n + 1];
    float ern = er[n];

    float m = -1e30f, s = 0.f;
    for (int i = beg + lane; i < end; i += 64) {
        float e = lrelu(el[srcidx[i]] + ern);
        if (e > m) { s = s * __expf(m - e) + 1.f; m = e; }
        else s += __expf(e - m);
    }
    #pragma unroll
    for (int o = 1; o < 64; o <<= 1) {
        float m2 = __shfl_xor(m, o), s2 = __shfl_xor(s, o);
        float M = fmaxf(m, m2);
        s = s * __expf(m - M) + s2 * __expf(m2 - M);
        m = M;
    }
    float inv = (s > 0.f) ? 1.f / s : 0.f;

    int q = lane >> 3, lcol = lane & 7;
    float a[8] = {};
    for (int i = beg + q; i < end; i += 8) {
        int sv = srcidx[i];
        float e = lrelu(el[sv] + ern);
        float p = __expf(e - m) * inv;
        uint4 v = *(const uint4*)&f2b[(size_t)sv * 64 + lcol * 8];
        a[0] = fmaf(bf2f(v.x & 0xffffu), p, a[0]);
        a[1] = fmaf(bf2f(v.x >> 16),     p, a[1]);
        a[2] = fmaf(bf2f(v.y & 0xffffu), p, a[2]);
        a[3] = fmaf(bf2f(v.y >> 16),     p, a[3]);
        a[4] = fmaf(bf2f(v.z & 0xffffu), p, a[4]);
        a[5] = fmaf(bf2f(v.z >> 16),     p, a[5]);
        a[6] = fmaf(bf2f(v.w & 0xffffu), p, a[6]);
        a[7] = fmaf(bf2f(v.w >> 16),     p, a[7]);
    }
    #pragma unroll
    for (int j = 0; j < 8; ++j) {
        a[j] += __shfl_xor(a[j], 8);
        a[j] += __shfl_xor(a[j], 16);
        a[j] += __shfl_xor(a[j], 32);
    }
    if (q == 0) {
        float4 o0, o1;
        o0.x = a[0] + bias[lcol * 8 + 0];
        o0.y = a[1] + bias[lcol * 8 + 1];
        o0.z = a[2] + bias[lcol * 8 + 2];
        o0.w = a[3] + bias[lcol * 8 + 3];
        o1.x = a[4] + bias[lcol * 8 + 4];
        o1.y = a[5] + bias[lcol * 8 + 5];
        o1.z = a[6] + bias[lcol * 8 + 6];
        o1.w = a[7] + bias[lcol * 8 + 7];
        *(float4*)&out[(size_t)n * 64 + lcol * 8] = o0;
        *(float4*)&out[(size_t)n * 64 + lcol * 8 + 4] = o1;
    }
}

// ---------------- launch ----------------

extern "C" void kernel_launch(void* const* d_in, const int* in_sizes, int n_in,
                              void* d_out, int out_size, void* d_ws, size_t ws_size,
                              hipStream_t stream) {
    const float* x      = (const float*)d_in[0];
    const int*   e0_src = (const int*)d_in[1];
    const int*   e0_dst = (const int*)d_in[2];
    const int*   e1_src = (const int*)d_in[3];
    const int*   e1_dst = (const int*)d_in[4];
    const float* W1     = (const float*)d_in[5];
    const float* al1    = (const float*)d_in[6];
    const float* ar1    = (const float*)d_in[7];
    const float* b1     = (const float*)d_in[8];
    const float* W2     = (const float*)d_in[9];
    const float* al2    = (const float*)d_in[10];
    const float* ar2    = (const float*)d_in[11];
    const float* b2     = (const float*)d_in[12];
    float* out = (float*)d_out;

    char* ws = (char*)d_ws;
    size_t off = 0;
    auto alloc = [&](size_t bytes) -> void* {
        void* p = ws + off;
        off = (off + bytes + 255) & ~(size_t)255;
        return p;
    };
    unsigned short* fb  = (unsigned short*)alloc((size_t)cN0 * 256 * 2);
    unsigned short* h1b = (unsigned short*)alloc((size_t)cN1 * 256 * 2);
    unsigned short* f2b = (unsigned short*)alloc((size_t)cN1 * 64 * 2);
    float* el0  = (float*)alloc((size_t)cN0 * 4 * 4);
    float* er0  = (float*)alloc((size_t)cN1 * 4 * 4);
    float* el2  = (float*)alloc((size_t)cN1 * 4);
    float* er2  = (float*)alloc((size_t)cN2 * 4);
    short* bt1  = (short*)alloc((size_t)256 * 256 * 2);
    short* bt2  = (short*)alloc((size_t)64 * 256 * 2);
    int* cntB    = (int*)alloc((size_t)(cN1 + cN2) * 4);
    int* cnt0    = cntB;
    int* cnt1    = cntB + cN1;
    int* offs0   = (int*)alloc((size_t)(cN1 + 1) * 4);
    int* cursor0 = (int*)alloc((size_t)cN1 * 4);
    int* srcidx0 = (int*)alloc((size_t)cE0 * 4);
    int* offs1   = (int*)alloc((size_t)(cN2 + 1) * 4);
    int* cursor1 = (int*)alloc((size_t)cN2 * 4);
    int* srcidx1 = (int*)alloc((size_t)cE1 * 4);
    int* bsum0   = (int*)alloc(256 * 4);
    int* bsum1   = (int*)alloc(256 * 4);
    (void)ws_size; (void)n_in; (void)in_sizes; (void)out_size;

    const int nblk0 = (cN1 + 255) / 256;   // 196
    const int nblk1 = (cN2 + 255) / 256;   // 98

    hipMemsetAsync(cntB, 0, (size_t)(cN1 + cN2) * 4, stream);
    hist2t_kernel<<<(cE0 + cE1 + 255) / 256, 256, 0, stream>>>(e0_dst, e1_dst, cnt0, cnt1,
                                                               W1, W2, bt1, bt2);
    chunk_sum2_kernel<<<dim3(nblk0, 2), 256, 0, stream>>>(cnt0, cN1, cnt1, cN2, bsum0, bsum1, nblk1);
    chunk_scan2b_kernel<<<dim3(nblk0, 2), 256, 0, stream>>>(cnt0, cN1, cnt1, cN2, bsum0, bsum1,
                                                            offs0, cursor0, offs1, cursor1, nblk1);
    scatter2_kernel<<<(cE0 + cE1 + 255) / 256, 256, 0, stream>>>(e0_src, e0_dst, e1_src, e1_dst,
                                                                 cursor0, srcidx0, cursor1, srcidx1);

    // ----- layer 0 -----
    gemm0_deep<<<(cN0 + 127) / 128, 512, 0, stream>>>(x, bt1, fb, al1, ar1, el0, er0, cN0, cN1);
    agg0_kernel<<<(cN1 + 3) / 4, 256, 0, stream>>>(offs0, srcidx0, el0, er0, fb, b1, h1b);

    // ----- layer 1 -----
    gemm_bf16_fused<128, 64, 4, 1><<<dim3((cN1 + 127) / 128, 1), 256, 0, stream>>>(
        h1b, bt2, f2b, al2, ar2, el2, er2, cN1, 256, 1, cN2);
    agg1_kernel<<<(cN2 + 3) / 4, 256, 0, stream>>>(offs1, srcidx1, el2, er2, f2b, b2, out);
}